// Round 7
// baseline (505.017 us; speedup 1.0000x reference)
//
#include <hip/hip_runtime.h>

#define HIDDEN 5120
#define NEXP 160
#define NGRP 8
#define GSIZE 20
#define TOPKG 3
#define TOPK 6

#define KSP 2                    // K-split (partial planes)
#define BT 128                   // tokens per gemm block (8 waves x 16)
#define KC 32                    // k per chunk (= one MFMA k-step)
#define NSTEP (HIDDEN / 32)      // 160 global k-steps
#define KPB (HIDDEN / KSP)       // 2560 k per block
#define NCH (KPB / KC)           // 80 chunks per block
#define CHU 1280                 // f16x8 units per packed-B chunk (640 hi + 640 lo)
#define F16_MIN_NORM 6.104e-5f   // denorm guard: MFMA may flush f16 denorms

typedef _Float16 f16;
typedef _Float16 f16x8 __attribute__((ext_vector_type(8)));
typedef float f32x4 __attribute__((ext_vector_type(4)));

__device__ __forceinline__ void gl_lds16(const void* g, void* l) {
    __builtin_amdgcn_global_load_lds((const __attribute__((address_space(1))) void*)g,
                                     (__attribute__((address_space(3))) void*)l, 16, 0, 0);
}

// ---------- K0: pack W fp32 -> chunk-contiguous f16 hi/lo in MFMA B-frag order ----
// chunk s (k-step of 32): unit u<640: hi, f=u/64, lane=u%64 -> w[f*16+(l&15)][s*32+(l>>4)*8+j]
//                         unit 640+u: matching lo = (w - f16(w)) * 4096
__global__ __launch_bounds__(256) void pack_w(const float* __restrict__ w,
                                              f16* __restrict__ bpk) {
    int idx = blockIdx.x * 256 + threadIdx.x;
    if (idx >= NSTEP * 10 * 64) return;
    int l = idx & 63;
    int rest = idx >> 6;
    int f = rest % 10;
    int s = rest / 10;
    int n = f * 16 + (l & 15);
    int k0 = s * 32 + (l >> 4) * 8;
    const float* src = w + (size_t)n * HIDDEN + k0;
    f16x8 hi, lo;
#pragma unroll
    for (int j = 0; j < 8; ++j) {
        float v = src[j];
        f16 hv = (fabsf(v) < F16_MIN_NORM) ? (f16)0.f : (f16)v;
        hi[j] = hv;
        lo[j] = (f16)((v - (float)hv) * 4096.0f);
    }
    f16x8* dst = (f16x8*)bpk;
    dst[(size_t)s * CHU + f * 64 + l] = hi;
    dst[(size_t)s * CHU + 640 + f * 64 + l] = lo;
}

// ---------- K1: split-f16 MFMA GEMM, partials [KSP][T][160] f32 ----------
// 8 waves/block; wave = 16 tokens (1 M-frag) x 160 experts (10 N-frags).
// A: lane-owned, f32 direct from global (nontemporal), 2-chunk-deep prefetch
//    (~32 KB in flight per CU to cover ~900cy HBM latency), hi/lo f16 in-register.
// B: 20 KB/chunk staged to LDS via global_load_lds (waves 0..4), double-buffered.
// Per-CU per-chunk: HBM 16 KB (~1600 cy, binding) > LDS ~800 > MFMA ~290.
__global__ __launch_bounds__(512, 2) void gemm_mfma(const float* __restrict__ x,
                                                    const f16* __restrict__ bpk,
                                                    float* __restrict__ part, int T) {
    __shared__ __align__(16) f16 Blds[2][CHU * 8];   // 20 KB per buf

    const int tid  = threadIdx.x;
    const int lane = tid & 63;
    const int wv   = tid >> 6;                  // 0..7
    const int tile = blockIdx.x >> 1;
    const int ks   = blockIdx.x & 1;
    const int t0   = tile * BT;
    const int m16  = lane & 15, h4 = lane >> 4;

    // this lane's A row, k-octet h4
    const float* xr = x + (size_t)(t0 + wv * 16 + m16) * HIDDEN + (size_t)ks * KPB + h4 * 8;

    const f16x8* bpk8 = (const f16x8*)bpk + (size_t)(ks * NCH) * CHU;

    auto stageB = [&](int b, int c) {
        if (wv < 5) {                           // wave-uniform: waves 0..4 x 4 units = 20
            const f16x8* src = bpk8 + (size_t)c * CHU + wv * 256 + lane;
            f16* dst = Blds[b] + (size_t)wv * 256 * 8;
#pragma unroll
            for (int i = 0; i < 4; ++i)
                gl_lds16(src + i * 64, dst + (size_t)i * 64 * 8);
        }
    };

    auto cvt8 = [&](f32x4 a, f32x4 b, f16x8& hi, f16x8& lo) {
#pragma unroll
        for (int j = 0; j < 8; ++j) {
            float v = (j < 4) ? a[j] : b[j - 4];
            f16 hv = (fabsf(v) < F16_MIN_NORM) ? (f16)0.f : (f16)v;
            hi[j] = hv;
            lo[j] = (f16)((v - (float)hv) * 4096.0f);
        }
    };

    f32x4 acc0[10], acc1[10];
    const f32x4 z4 = {0.f, 0.f, 0.f, 0.f};
#pragma unroll
    for (int nf = 0; nf < 10; ++nf) { acc0[nf] = z4; acc1[nf] = z4; }

    // prologue: B chunk 0 -> buf 0; x chunks 0 (convert) and 1 (in flight)
    stageB(0, 0);
    f32x4 ca = __builtin_nontemporal_load((const f32x4*)xr);
    f32x4 cb = __builtin_nontemporal_load((const f32x4*)(xr + 4));
    f32x4 na = __builtin_nontemporal_load((const f32x4*)(xr + KC));
    f32x4 nb = __builtin_nontemporal_load((const f32x4*)(xr + KC + 4));
    f16x8 ah, al;
    cvt8(ca, cb, ah, al);
    __syncthreads();

    int buf = 0;
    for (int c = 0; c < NCH; ++c) {
        f32x4 fa, fb;
        if (c + 2 < NCH) {                      // issue chunk c+2 loads (2-deep)
            const float* nx = xr + (size_t)(c + 2) * KC;
            fa = __builtin_nontemporal_load((const f32x4*)nx);
            fb = __builtin_nontemporal_load((const f32x4*)(nx + 4));
        }
        if (c + 1 < NCH) stageB(buf ^ 1, c + 1);

        const f16* Bb = Blds[buf];
#pragma unroll
        for (int nf = 0; nf < 10; ++nf) {
            f16x8 bh = *(const f16x8*)&Bb[(nf * 64 + lane) * 8];
            f16x8 bl = *(const f16x8*)&Bb[((640 + nf * 64) + lane) * 8];
            acc0[nf] = __builtin_amdgcn_mfma_f32_16x16x32_f16(ah, bh, acc0[nf], 0, 0, 0);
            acc1[nf] = __builtin_amdgcn_mfma_f32_16x16x32_f16(ah, bl, acc1[nf], 0, 0, 0);
            acc1[nf] = __builtin_amdgcn_mfma_f32_16x16x32_f16(al, bh, acc1[nf], 0, 0, 0);
        }

        if (c + 1 < NCH) {                      // convert chunk c+1 (its loads are oldest)
            cvt8(na, nb, ah, al);
            na = fa; nb = fb;                   // rotate (static regs, rule #20)
        }
        __syncthreads();
        buf ^= 1;
    }

    // epilogue: logit = acc0 + acc1/4096; C/D: col=lane&15 (expert), row=h4*4+r (token)
    const float s12 = 1.0f / 4096.0f;
    const int tb = t0 + wv * 16 + h4 * 4;
#pragma unroll
    for (int nf = 0; nf < 10; ++nf) {
        int e = nf * 16 + m16;
#pragma unroll
        for (int r = 0; r < 4; ++r)
            part[((size_t)ks * T + tb + r) * NEXP + e] = acc0[nf][r] + acc1[nf][r] * s12;
    }
}

// ---------- K2: 8 lanes per token: combine partials + grouped top-k ----------
__global__ __launch_bounds__(512) void moe_topk3(const float* __restrict__ part,
                                                 float* __restrict__ out, int T) {
    const int tid = threadIdx.x;
    const int tl  = tid >> 3;
    const int g   = tid & 7;
    const int t   = blockIdx.x * 64 + tl;

    const float* r0 = part + (size_t)t * NEXP + g * GSIZE;
    const size_t plane = (size_t)T * NEXP;

    float v[GSIZE];
    float gmx = -3e38f;
#pragma unroll
    for (int j = 0; j < 5; ++j) {
        f32x4 s = *(const f32x4*)(r0 + j * 4);
#pragma unroll
        for (int p = 1; p < KSP; ++p) {
            f32x4 a = *(const f32x4*)(r0 + (size_t)p * plane + j * 4);
            s[0] += a[0]; s[1] += a[1]; s[2] += a[2]; s[3] += a[3];
        }
#pragma unroll
        for (int cc = 0; cc < 4; ++cc) {
            v[j * 4 + cc] = s[cc];
            gmx = fmaxf(gmx, s[cc]);
        }
    }

    float gm[NGRP];
#pragma unroll
    for (int i = 0; i < NGRP; ++i) gm[i] = __shfl(gmx, i, 8);

    // top-3 groups, lowest index wins ties (matches stable lax.top_k)
    unsigned gmask = 0;
#pragma unroll
    for (int r = 0; r < TOPKG; ++r) {
        float bv = -3e38f; int bi = 0;
#pragma unroll
        for (int gg = 0; gg < NGRP; ++gg) {
            bool elig = !((gmask >> gg) & 1);
            if (elig && gm[gg] > bv) { bv = gm[gg]; bi = gg; }
        }
        gmask |= 1u << bi;
    }
    const bool sel = (gmask >> g) & 1;

    // local stable top-6 of my group (value desc, index asc)
    float lv[TOPK]; int li[TOPK];
#pragma unroll
    for (int r = 0; r < TOPK; ++r) { lv[r] = -3e38f; li[r] = 1 << 20; }
    if (sel) {
#pragma unroll
        for (int j = 0; j < GSIZE; ++j) {
            float sv = v[j];
            int e = g * GSIZE + j;
            if (sv > lv[TOPK - 1]) {
                lv[TOPK - 1] = sv; li[TOPK - 1] = e;
#pragma unroll
                for (int q = TOPK - 1; q > 0; --q) {
                    if (lv[q] > lv[q - 1]) {
                        float tv = lv[q]; lv[q] = lv[q - 1]; lv[q - 1] = tv;
                        int ti = li[q]; li[q] = li[q - 1]; li[q - 1] = ti;
                    }
                }
            }
        }
    }

    // 8-way merge: butterfly argmax of list heads (tie -> lower e), winner pops
    float vals[TOPK]; int idxs[TOPK];
#pragma unroll
    for (int r = 0; r < TOPK; ++r) {
        float cv = lv[0]; int ce = li[0];
        float bv = cv; int be = ce;
#pragma unroll
        for (int m = 1; m < 8; m <<= 1) {
            float ov = __shfl_xor(bv, m, 8);
            int   oe = __shfl_xor(be, m, 8);
            if (ov > bv || (ov == bv && oe < be)) { bv = ov; be = oe; }
        }
        vals[r] = bv; idxs[r] = be;
        if (be == ce) {
#pragma unroll
            for (int q = 0; q < TOPK - 1; ++q) { lv[q] = lv[q + 1]; li[q] = li[q + 1]; }
            lv[TOPK - 1] = -3e38f; li[TOPK - 1] = 1 << 20;
        }
    }

    if (g == 0) {
        float m0 = vals[0], ssum = 0.f, w6[TOPK];
#pragma unroll
        for (int r = 0; r < TOPK; ++r) { w6[r] = expf(vals[r] - m0); ssum += w6[r]; }
        float inv = 1.f / (ssum + 1e-20f);
#pragma unroll
        for (int r = 0; r < TOPK; ++r) {
            out[(size_t)t * TOPK + r] = (float)idxs[r];
            out[(size_t)T * TOPK + (size_t)t * TOPK + r] = w6[r] * inv;
        }
    }
}

extern "C" void kernel_launch(void* const* d_in, const int* in_sizes, int n_in,
                              void* d_out, int out_size, void* d_ws, size_t ws_size,
                              hipStream_t stream) {
    const float* x = (const float*)d_in[0];
    const float* w = (const float*)d_in[1];
    float* out = (float*)d_out;
    const int T = in_sizes[0] / HIDDEN;  // 16384

    f16* bpk    = (f16*)d_ws;                              // 3.28 MB packed B (hi+lo)
    float* part = (float*)d_ws + (size_t)HIDDEN * NEXP;    // KSP * T * 160 f32 (21 MB)

    pack_w<<<(NSTEP * 10 * 64 + 255) / 256, 256, 0, stream>>>(w, bpk);
    gemm_mfma<<<(T / BT) * KSP, 512, 0, stream>>>(x, bpk, part, T);  // 256 blocks = 1/CU
    moe_topk3<<<T / 64, 512, 0, stream>>>(part, out, T);
}